// Round 19
// baseline (82.411 us; speedup 1.0000x reference)
//
#include <hip/hip_runtime.h>
#include <stdint.h>

#define HH 64
#define WW 64
#define PIN 64
#define POUT 64
#define NFEAT 54
#define SEGB 16384     // 2 features x 8192 B per segment
#define NSEG 27
#define NPROBE 4

typedef _Float16 half8 __attribute__((ext_vector_type(8)));
typedef _Float16 half4 __attribute__((ext_vector_type(4)));
typedef float f32x4 __attribute__((ext_vector_type(4)));
typedef float f32x16 __attribute__((ext_vector_type(16)));

__device__ constexpr int KT[54] = {0,0,0,0,0,0,0,0,0, 1,1,1,1,1,1,1,1,1, 2,2,2,2,2,2,2,2,
                                   3,3,3,3,3,3,3, 4,4,4,4,4,4, 5,5,5,5,5, 6,6,6,6, 7,7,7, 8,8, 9};
__device__ constexpr int LT[54] = {1,2,3,4,5,6,7,8,9, 1,2,3,4,5,6,7,8,9, 2,3,4,5,6,7,8,9,
                                   3,4,5,6,7,8,9, 4,5,6,7,8,9, 5,6,7,8,9, 6,7,8,9, 7,8,9, 8,9, 9};

// ---------------- filter prep (r17 verified, ~0.2us) ----------------
__global__ __launch_bounds__(256) void prep_filters(
    const float* __restrict__ f, const float* __restrict__ bias,
    _Float16* __restrict__ fprep, float* __restrict__ fconst) {
    __shared__ float lds_f[6400];

    const int o = blockIdx.x;
    const int t = threadIdx.x;
    const float* fo = f + (size_t)o * 6400;

    for (int i = t; i < 6400; i += 256) lds_f[i] = fo[i];
    __syncthreads();

    if (t < 64) {
        float v = lds_f[t * 100];
        #pragma unroll
        for (int m = 32; m >= 1; m >>= 1) v += __shfl_xor(v, m, 64);
        if (t == 0) fconst[o] = bias[o] + v;
    }

    for (int q = t; q < NFEAT * 8; q += 256) {
        int feat = q >> 3;
        int cg = q & 7;
        int k = KT[feat], l = LT[feat];
        half8 chunk;
        #pragma unroll
        for (int jj = 0; jj < 8; ++jj) {
            const float* fc = lds_f + (cg * 8 + jj) * 100;
            float v;
            if (k == 0)      v = fc[l] + fc[l * 10];
            else if (k == l) v = fc[k * 10 + k];
            else             v = fc[k * 10 + l] + fc[l * 10 + k];
            chunk[jj] = (_Float16)v;
        }
        size_t byte = (size_t)feat * 8192 + (cg >> 1) * 2048 + (o >> 5) * 1024
                    + ((o & 31) + 32 * (cg & 1)) * 16;
        *(half8*)((char*)fprep + byte) = chunk;
    }
}

#define STAGE_IMPL(ss, smBp)                                                              \
    do {                                                                                  \
        const char* s_ = (const char*)fprep + (size_t)(ss) * SEGB;                        \
        _Pragma("unroll")                                                                 \
        for (int r_ = 0; r_ < 2; ++r_)                                                    \
            __builtin_amdgcn_global_load_lds(                                             \
                (const __attribute__((address_space(1))) unsigned int*)(const void*)(s_ + r_ * 8192 + t * 16), \
                (__attribute__((address_space(3))) unsigned int*)(void*)((smBp) + ((ss) & 1) * SEGB + r_ * 8192 + (wid << 10)), \
                16, 0, 0);                                                                \
    } while (0)

// ---------------- main MFMA kernel (byte-identical to r18) ----------------
__global__ __launch_bounds__(512, 4) void poly2d_mfma(
    const float* __restrict__ x, const _Float16* __restrict__ fprep,
    const float* __restrict__ fconst, float* __restrict__ out)
{
    __shared__ __align__(16) char smB[2 * SEGB];
    __shared__ __align__(16) char smx[25344];

    const int t = threadIdx.x;
    const int lane = t & 63;
    const int wid = t >> 6;
    const int bid = (blockIdx.x & 7) * 64 + (blockIdx.x >> 3);
    const int b = bid >> 6;
    const int hrow = bid & 63;

    STAGE_IMPL(0, smB);
    STAGE_IMPL(1, smB);

    {
        const int w = t & 63;
        const int wl = w + 1;
        #pragma unroll
        for (int h = 0; h < 3; ++h) {
            int h_in = hrow - 1 + h;
            bool hok = ((unsigned)h_in < HH);
            #pragma unroll
            for (int cc = 0; cc < 2; ++cc) {
                int c = wid * 8 + cc * 4;
                float v0 = 0.f, v1 = 0.f, v2 = 0.f, v3 = 0.f;
                if (hok) {
                    const float* gx = x + (((size_t)b * PIN + c) * HH + h_in) * WW + w;
                    v0 = gx[0]; v1 = gx[4096]; v2 = gx[8192]; v3 = gx[12288];
                }
                half4 pk = {(_Float16)v0, (_Float16)v1, (_Float16)v2, (_Float16)v3};
                int byte = ((h * 66 + wl) * 8 + ((c >> 3) ^ (wl & 7))) * 16 + (c & 7) * 2;
                *(half4*)(smx + byte) = pk;
            }
        }
        if (t < 48) {
            int h = t >> 4, side = (t >> 3) & 1, cg = t & 7;
            int wl2 = side ? 65 : 0;
            int byte = ((h * 66 + wl2) * 8 + (cg ^ (wl2 & 7))) * 16;
            f32x4 z = {0.f, 0.f, 0.f, 0.f};
            *(f32x4*)(smx + byte) = z;
        }
    }
    __syncthreads();

    const int kc = wid >> 1;
    const int mwid = wid & 1;
    const int wbase = mwid * 32;
    const int l31 = lane & 31;
    const int lhi = lane >> 5;

    half8 xp[9];
    #pragma unroll
    for (int p = 1; p <= 9; ++p) {
        const int dh = (p - 1) / 3 - 1, dw = (p - 1) % 3 - 1;
        int wl = wbase + l31 + dw + 1;
        int hidx = dh + 1;
        int cgl = kc * 2 + lhi;
        int byte = ((hidx * 66 + wl) * 8 + (cgl ^ (wl & 7))) * 16;
        xp[p - 1] = *(const half8*)(smx + byte);
    }
    __syncthreads();

    f32x16 acc0 = {}, acc1 = {};
    const int boff = (kc << 11) + (lane << 4);

    #pragma unroll
    for (int s = 0; s < NSEG; ++s) {
        if (s == NSEG - 1) { asm volatile("s_waitcnt vmcnt(0)" ::: "memory"); }
        else               { asm volatile("s_waitcnt vmcnt(2)" ::: "memory"); }
        asm volatile("" ::: "memory");
        __builtin_amdgcn_s_barrier();
        asm volatile("" ::: "memory");

        const char* bseg = smB + (s & 1) * SEGB + boff;
        half8 Bb0[2], Bb1[2];
        #pragma unroll
        for (int j = 0; j < 2; ++j) {
            Bb0[j] = *(const half8*)(bseg + j * 8192);
            Bb1[j] = *(const half8*)(bseg + j * 8192 + 1024);
        }
        #pragma unroll
        for (int j = 0; j < 2; ++j) {
            const int f = s * 2 + j;
            const int k = KT[f], l = LT[f];
            half8 a = (k == 0) ? xp[l - 1] : xp[k - 1] * xp[l - 1];
            acc0 = __builtin_amdgcn_mfma_f32_32x32x16_f16(a, Bb0[j], acc0, 0, 0, 0);
            acc1 = __builtin_amdgcn_mfma_f32_32x32x16_f16(a, Bb1[j], acc1, 0, 0, 0);
        }

        asm volatile("s_waitcnt lgkmcnt(0)" ::: "memory");
        asm volatile("" ::: "memory");
        __builtin_amdgcn_s_barrier();
        asm volatile("" ::: "memory");
        if (s + 2 < NSEG) STAGE_IMPL(s + 2, smB);
    }

    __syncthreads();
    float* os = (float*)smx;

    #pragma unroll
    for (int pass = 0; pass < 4; ++pass) {
        if (kc == pass) {
            #pragma unroll
            for (int nb = 0; nb < 2; ++nb) {
                #pragma unroll
                for (int r = 0; r < 16; ++r) {
                    int row = (r & 3) + 8 * (r >> 2) + 4 * lhi;
                    int m = mwid * 32 + row;
                    int col = l31 + nb * 32;
                    float v = nb ? acc1[r] : acc0[r];
                    if (pass == 0) os[m * 65 + col] = v;
                    else           os[m * 65 + col] += v;
                }
            }
        }
        __syncthreads();
    }

    {
        const int w = t & 63;
        #pragma unroll
        for (int oo = 0; oo < 8; ++oo) {
            int o = wid * 8 + oo;
            float val = os[w * 65 + o] + fconst[o];
            out[(((size_t)b * POUT + o) * HH + hrow) * WW + w] = val;
        }
    }
}

// ---------------- ABLATION PROBE: r18 phase engine only ----------------
// Identical grid/block/launch-bounds/LDS footprint and phase loop (STAGE +
// counted vmcnt + 2 barriers + ds_read_b128 + MFMA), with x-stage, xp-loads
// and epilogue removed (A = constants; 1 f32/thread result into ws).
// T_probe = (dur - 29.4 - gaps) / NPROBE isolates the loop engine cost.
__global__ __launch_bounds__(512, 4) void loop_probe(
    const _Float16* __restrict__ fprep, float* __restrict__ ws_out)
{
    __shared__ __align__(16) char smB[2 * SEGB];
    __shared__ __align__(16) char smx[25344];   // footprint parity with main

    const int t = threadIdx.x;
    const int lane = t & 63;
    const int wid = t >> 6;
    const int kc = wid >> 1;

    if (t == 0) ((volatile char*)smx)[0] = 1;   // keep smx allocated

    STAGE_IMPL(0, smB);
    STAGE_IMPL(1, smB);
    __syncthreads();

    half8 c1, c2;
    #pragma unroll
    for (int j = 0; j < 8; ++j) {
        c1[j] = (_Float16)(float)((lane + j) & 7);
        c2[j] = (_Float16)0.5f;
    }

    f32x16 acc0 = {}, acc1 = {};
    const int boff = (kc << 11) + (lane << 4);

    #pragma unroll
    for (int s = 0; s < NSEG; ++s) {
        if (s == NSEG - 1) { asm volatile("s_waitcnt vmcnt(0)" ::: "memory"); }
        else               { asm volatile("s_waitcnt vmcnt(2)" ::: "memory"); }
        asm volatile("" ::: "memory");
        __builtin_amdgcn_s_barrier();
        asm volatile("" ::: "memory");

        const char* bseg = smB + (s & 1) * SEGB + boff;
        half8 Bb0[2], Bb1[2];
        #pragma unroll
        for (int j = 0; j < 2; ++j) {
            Bb0[j] = *(const half8*)(bseg + j * 8192);
            Bb1[j] = *(const half8*)(bseg + j * 8192 + 1024);
        }
        #pragma unroll
        for (int j = 0; j < 2; ++j) {
            half8 a = c1 * c2;
            acc0 = __builtin_amdgcn_mfma_f32_32x32x16_f16(a, Bb0[j], acc0, 0, 0, 0);
            acc1 = __builtin_amdgcn_mfma_f32_32x32x16_f16(a, Bb1[j], acc1, 0, 0, 0);
        }

        asm volatile("s_waitcnt lgkmcnt(0)" ::: "memory");
        asm volatile("" ::: "memory");
        __builtin_amdgcn_s_barrier();
        asm volatile("" ::: "memory");
        if (s + 2 < NSEG) STAGE_IMPL(s + 2, smB);
    }

    float sum = 0.f;
    #pragma unroll
    for (int r = 0; r < 16; ++r) sum += acc0[r] + acc1[r];
    ws_out[(size_t)blockIdx.x * 512 + t] = sum;
}

// ---------------- fp32 fallback ----------------
__global__ __launch_bounds__(256) void poly2d_fp32(
    const float* __restrict__ x, const float* __restrict__ f,
    const float* __restrict__ bias, float* __restrict__ out)
{
    const int t = threadIdx.x;
    const int wo = t & 63;
    const int ho = (blockIdx.x & 15) * 4 + (t >> 6);
    const int o = (blockIdx.x >> 4) & 63;
    const int b = blockIdx.x >> 10;

    float acc = bias[o];
    const float* xb = x + (size_t)b * PIN * HH * WW;
    const float* fo = f + (size_t)o * PIN * 100;
    for (int c = 0; c < PIN; ++c) {
        const float* xc = xb + (size_t)c * HH * WW;
        float s[10];
        s[0] = 1.0f;
        #pragma unroll
        for (int kh = 0; kh < 3; ++kh) {
            int h = ho - 1 + kh;
            bool hok = ((unsigned)h < HH);
            #pragma unroll
            for (int kw = 0; kw < 3; ++kw) {
                int w = wo - 1 + kw;
                s[1 + kh * 3 + kw] = (hok && (unsigned)w < WW) ? xc[h * WW + w] : 0.0f;
            }
        }
        const float* fc = fo + c * 100;
        #pragma unroll
        for (int i = 0; i < 10; ++i) {
            float wsum = 0.0f;
            #pragma unroll
            for (int j = 0; j < 10; ++j) wsum = fmaf(fc[i * 10 + j], s[j], wsum);
            acc = fmaf(wsum, s[i], acc);
        }
    }
    out[(((size_t)b * POUT + o) * HH + ho) * WW + wo] = acc;
}

extern "C" void kernel_launch(void* const* d_in, const int* in_sizes, int n_in,
                              void* d_out, int out_size, void* d_ws, size_t ws_size,
                              hipStream_t stream) {
    const float* x    = (const float*)d_in[0];
    const float* filt = (const float*)d_in[1];
    const float* bias = (const float*)d_in[2];
    float* out = (float*)d_out;

    const size_t FPREP_BYTES = (size_t)NFEAT * POUT * PIN * 2; // 442368
    if (ws_size < FPREP_BYTES + 256) {
        poly2d_fp32<<<dim3(8 * 64 * 16), dim3(256), 0, stream>>>(x, filt, bias, out);
        return;
    }
    _Float16* fprep = (_Float16*)d_ws;
    float* fconst = (float*)((char*)d_ws + FPREP_BYTES);

    prep_filters<<<dim3(64), dim3(256), 0, stream>>>(filt, bias, fprep, fconst);
    poly2d_mfma<<<dim3(512), dim3(512), 0, stream>>>(x, fprep, fconst, out);

    // ---- ablation probes (diagnostic): 4 sequential copies of the phase engine ----
    if (ws_size >= (8u << 20)) {
        float* probe_out = (float*)((char*)d_ws + (4u << 20));
        for (int i = 0; i < NPROBE; ++i)
            loop_probe<<<dim3(512), dim3(512), 0, stream>>>(fprep, probe_out);
    }
}

// Round 20
// 27.977 us; speedup vs baseline: 2.9457x; 2.9457x over previous
//
#include <hip/hip_runtime.h>
#include <stdint.h>

#define HH 64
#define WW 64
#define PIN 64
#define POUT 64
#define NFEAT 54
#define SEGB 16384     // 2 features x 8192 B per segment
#define NSEG 27

typedef _Float16 half8 __attribute__((ext_vector_type(8)));
typedef _Float16 half4 __attribute__((ext_vector_type(4)));
typedef float f32x4 __attribute__((ext_vector_type(4)));
typedef float f32x16 __attribute__((ext_vector_type(16)));

// constexpr (NOT __constant__): folds to literals under full unroll (rule #20).
__device__ constexpr int KT[54] = {0,0,0,0,0,0,0,0,0, 1,1,1,1,1,1,1,1,1, 2,2,2,2,2,2,2,2,
                                   3,3,3,3,3,3,3, 4,4,4,4,4,4, 5,5,5,5,5, 6,6,6,6, 7,7,7, 8,8, 9};
__device__ constexpr int LT[54] = {1,2,3,4,5,6,7,8,9, 1,2,3,4,5,6,7,8,9, 2,3,4,5,6,7,8,9,
                                   3,4,5,6,7,8,9, 4,5,6,7,8,9, 5,6,7,8,9, 6,7,8,9, 7,8,9, 8,9, 9};

// ---------------- filter prep (r17 verified coalesced two-pass) ----------------
// Fragment order: byte(f,o,c) = f*8192 + (c>>4)*2048 + (o>>5)*1024
//                + ((o&31)+32*((c>>3)&1))*16 + (c&7)*2
__global__ __launch_bounds__(256) void prep_filters(
    const float* __restrict__ f, const float* __restrict__ bias,
    _Float16* __restrict__ fprep, float* __restrict__ fconst) {
    __shared__ float lds_f[6400];

    const int o = blockIdx.x;
    const int t = threadIdx.x;
    const float* fo = f + (size_t)o * 6400;

    for (int i = t; i < 6400; i += 256) lds_f[i] = fo[i];
    __syncthreads();

    if (t < 64) {
        float v = lds_f[t * 100];
        #pragma unroll
        for (int m = 32; m >= 1; m >>= 1) v += __shfl_xor(v, m, 64);
        if (t == 0) fconst[o] = bias[o] + v;
    }

    for (int q = t; q < NFEAT * 8; q += 256) {
        int feat = q >> 3;
        int cg = q & 7;
        int k = KT[feat], l = LT[feat];
        half8 chunk;
        #pragma unroll
        for (int jj = 0; jj < 8; ++jj) {
            const float* fc = lds_f + (cg * 8 + jj) * 100;
            float v;
            if (k == 0)      v = fc[l] + fc[l * 10];
            else if (k == l) v = fc[k * 10 + k];
            else             v = fc[k * 10 + l] + fc[l * 10 + k];
            chunk[jj] = (_Float16)v;
        }
        size_t byte = (size_t)feat * 8192 + (cg >> 1) * 2048 + (o >> 5) * 1024
                    + ((o & 31) + 32 * (cg & 1)) * 16;
        *(half8*)((char*)fprep + byte) = chunk;
    }
}

// ---------------- main MFMA kernel: 64m waves + LDS tri-buffer ----------------
// grid 256 = b(8) x rowpair(32) XCD-swizzled; block 512 = 8 waves =
// 2 m-supers (64 px = one row) x 4 kc-quarters (K=16). Each wave holds TWO
// A-frags (w-halves of its row) so every B-fragment read feeds 4 MFMAs ->
// per-CU B LDS-read traffic halves vs r18 (the r19 probe showed the engine is
// LDS/L2-BW-bound, not barrier-bound). B via tri-buffered 16KB segments,
// linear global_load_lds, counted vmcnt(4) (prefetch distance 3 phases).
__global__ __launch_bounds__(512, 2) void poly2d_mfma(
    const float* __restrict__ x, const _Float16* __restrict__ fprep,
    const float* __restrict__ fconst, float* __restrict__ out)
{
    __shared__ __align__(16) char smB[3 * SEGB];  // B tri-buffer: 3 x 2 feat x 8192
    __shared__ __align__(16) char smx[33792];     // x tile [4][64][8cg swz][16B]; reused as os[128][65] f32

    const int t = threadIdx.x;
    const int lane = t & 63;
    const int wid = t >> 6;            // 0..7
    // XCD-bijective swizzle (256 % 8 == 0)
    const int bid = (blockIdx.x & 7) * 32 + (blockIdx.x >> 3);
    const int b = bid >> 5;
    const int rp = bid & 31;           // output rows rp*2, rp*2+1

#define STAGE(ss)                                                                         \
    do {                                                                                  \
        const char* s_ = (const char*)fprep + (size_t)(ss) * SEGB;                        \
        _Pragma("unroll")                                                                 \
        for (int r_ = 0; r_ < 2; ++r_)                                                    \
            __builtin_amdgcn_global_load_lds(                                             \
                (const __attribute__((address_space(1))) unsigned int*)(const void*)(s_ + r_ * 8192 + t * 16), \
                (__attribute__((address_space(3))) unsigned int*)(void*)(smB + ((ss) % 3) * SEGB + r_ * 8192 + (wid << 10)), \
                16, 0, 0);                                                                \
    } while (0)

    // prologue: stage segments 0,1,2 (6 loads/thread); first __syncthreads drains
    STAGE(0);
    STAGE(1);
    STAGE(2);

    // ---- stage x tile (rows rp*2-1..rp*2+2, w 0..63, 64 c) swizzled fp16 ----
    {
        const int w = t & 63;
        #pragma unroll
        for (int h = 0; h < 4; ++h) {
            int h_in = rp * 2 - 1 + h;
            bool hok = ((unsigned)h_in < HH);
            #pragma unroll
            for (int cc = 0; cc < 2; ++cc) {
                int c = wid * 8 + cc * 4;  // channels c..c+3
                float v0 = 0.f, v1 = 0.f, v2 = 0.f, v3 = 0.f;
                if (hok) {
                    const float* gx = x + (((size_t)b * PIN + c) * HH + h_in) * WW + w;
                    v0 = gx[0]; v1 = gx[4096]; v2 = gx[8192]; v3 = gx[12288];
                }
                half4 pk = {(_Float16)v0, (_Float16)v1, (_Float16)v2, (_Float16)v3};
                int byte = ((h * 64 + w) * 8 + ((c >> 3) ^ (w & 7))) * 16 + (c & 7) * 2;
                *(half4*)(smx + byte) = pk;
            }
        }
    }
    __syncthreads(); // drains vmcnt+lgkm: x tile ready, segments 0-2 landed or in flight

    const int kc = wid >> 1;           // 0..3 channel quarter
    const int msup = wid & 1;          // m-super = output row within pair
    const int l31 = lane & 31;
    const int lhi = lane >> 5;         // 0/1

    // ---- load 9 shift panels x 2 w-halves (A-frag: m=lane&31 -> w, k=lhi*8+e) ----
    half8 xp[9][2];
    #pragma unroll
    for (int p = 1; p <= 9; ++p) {
        const int dh = (p - 1) / 3 - 1, dw = (p - 1) % 3 - 1;
        #pragma unroll
        for (int mb = 0; mb < 2; ++mb) {
            int wl = mb * 32 + l31 + dw;          // -1..64
            int wc = wl < 0 ? 0 : (wl > 63 ? 63 : wl);
            int hidx = msup + dh + 1;             // 0..3
            int cgl = kc * 2 + lhi;
            int byte = ((hidx * 64 + wc) * 8 + (cgl ^ (wc & 7))) * 16;
            half8 v = *(const half8*)(smx + byte);
            if ((unsigned)wl >= 64u) v = half8{}; // w out of image -> 0
            xp[p - 1][mb] = v;
        }
    }
    __syncthreads(); // xp reads retired before smx becomes os

    f32x16 acc00 = {}, acc01 = {}, acc10 = {}, acc11 = {};
    const int boff = (kc << 11) + (lane << 4);

    // ---- 27 phases x 2 features: tri-buffer LDS B, counted vmcnt(4) ----
    #pragma unroll
    for (int s = 0; s < NSEG; ++s) {
        if (s < NSEG - 2)       { asm volatile("s_waitcnt vmcnt(4)" ::: "memory"); }
        else if (s == NSEG - 2) { asm volatile("s_waitcnt vmcnt(2)" ::: "memory"); }
        else                    { asm volatile("s_waitcnt vmcnt(0)" ::: "memory"); }
        asm volatile("" ::: "memory");
        __builtin_amdgcn_s_barrier();
        asm volatile("" ::: "memory");

        const char* bseg = smB + (s % 3) * SEGB + boff;
        #pragma unroll
        for (int j = 0; j < 2; ++j) {
            half8 b0 = *(const half8*)(bseg + j * 8192);
            half8 b1 = *(const half8*)(bseg + j * 8192 + 1024);
            const int f = s * 2 + j;          // unroll-constant -> KT/LT fold
            const int k = KT[f], l = LT[f];
            half8 a0 = (k == 0) ? xp[l - 1][0] : xp[k - 1][0] * xp[l - 1][0];
            half8 a1 = (k == 0) ? xp[l - 1][1] : xp[k - 1][1] * xp[l - 1][1];
            acc00 = __builtin_amdgcn_mfma_f32_32x32x16_f16(a0, b0, acc00, 0, 0, 0);
            acc01 = __builtin_amdgcn_mfma_f32_32x32x16_f16(a0, b1, acc01, 0, 0, 0);
            acc10 = __builtin_amdgcn_mfma_f32_32x32x16_f16(a1, b0, acc10, 0, 0, 0);
            acc11 = __builtin_amdgcn_mfma_f32_32x32x16_f16(a1, b1, acc11, 0, 0, 0);
        }

        asm volatile("s_waitcnt lgkmcnt(0)" ::: "memory"); // my ds_reads retired
        asm volatile("" ::: "memory");
        __builtin_amdgcn_s_barrier();                      // everyone's retired
        asm volatile("" ::: "memory");
        if (s + 3 < NSEG) STAGE(s + 3);   // overwrite slot (s%3), just freed
    }
#undef STAGE

    __syncthreads(); // loop done; smx free for output staging
    float* os = (float*)smx; // [128 px][65]  (px = row*64 + w)

    // reduce 4 kc partials (C/D: col=lane&31 (+nb*32), m=(r&3)+8*(r>>2)+4*lhi -> w-in-half)
#define EPI(ACC, MB, NB, OP)                                                              \
    do {                                                                                  \
        _Pragma("unroll")                                                                 \
        for (int r = 0; r < 16; ++r) {                                                    \
            int m = (r & 3) + 8 * (r >> 2) + 4 * lhi;                                     \
            int px = msup * 64 + (MB) * 32 + m;                                           \
            int col = l31 + (NB) * 32;                                                    \
            os[px * 65 + col] OP (ACC)[r];                                                \
        }                                                                                 \
    } while (0)

    #pragma unroll
    for (int pass = 0; pass < 4; ++pass) {
        if (kc == pass) {
            if (pass == 0) {
                EPI(acc00, 0, 0, =); EPI(acc01, 0, 1, =);
                EPI(acc10, 1, 0, =); EPI(acc11, 1, 1, =);
            } else {
                EPI(acc00, 0, 0, +=); EPI(acc01, 0, 1, +=);
                EPI(acc10, 1, 0, +=); EPI(acc11, 1, 1, +=);
            }
        }
        __syncthreads();
    }
#undef EPI

    { // coalesced store: lanes sweep w
        const int w = t & 63;
        #pragma unroll
        for (int h2 = 0; h2 < 2; ++h2) {
            #pragma unroll
            for (int oo = 0; oo < 8; ++oo) {
                int o = wid * 8 + oo;
                float val = os[(h2 * 64 + w) * 65 + o] + fconst[o];
                out[(((size_t)b * POUT + o) * HH + (rp * 2 + h2)) * WW + w] = val;
            }
        }
    }
}

// ---------------- fp32 fallback, used only if ws too small ----------------
__global__ __launch_bounds__(256) void poly2d_fp32(
    const float* __restrict__ x, const float* __restrict__ f,
    const float* __restrict__ bias, float* __restrict__ out)
{
    const int t = threadIdx.x;
    const int wo = t & 63;
    const int ho = (blockIdx.x & 15) * 4 + (t >> 6);
    const int o = (blockIdx.x >> 4) & 63;
    const int b = blockIdx.x >> 10;

    float acc = bias[o];
    const float* xb = x + (size_t)b * PIN * HH * WW;
    const float* fo = f + (size_t)o * PIN * 100;
    for (int c = 0; c < PIN; ++c) {
        const float* xc = xb + (size_t)c * HH * WW;
        float s[10];
        s[0] = 1.0f;
        #pragma unroll
        for (int kh = 0; kh < 3; ++kh) {
            int h = ho - 1 + kh;
            bool hok = ((unsigned)h < HH);
            #pragma unroll
            for (int kw = 0; kw < 3; ++kw) {
                int w = wo - 1 + kw;
                s[1 + kh * 3 + kw] = (hok && (unsigned)w < WW) ? xc[h * WW + w] : 0.0f;
            }
        }
        const float* fc = fo + c * 100;
        #pragma unroll
        for (int i = 0; i < 10; ++i) {
            float wsum = 0.0f;
            #pragma unroll
            for (int j = 0; j < 10; ++j) wsum = fmaf(fc[i * 10 + j], s[j], wsum);
            acc = fmaf(wsum, s[i], acc);
        }
    }
    out[(((size_t)b * POUT + o) * HH + ho) * WW + wo] = acc;
}

extern "C" void kernel_launch(void* const* d_in, const int* in_sizes, int n_in,
                              void* d_out, int out_size, void* d_ws, size_t ws_size,
                              hipStream_t stream) {
    const float* x    = (const float*)d_in[0];
    const float* filt = (const float*)d_in[1];
    const float* bias = (const float*)d_in[2];
    float* out = (float*)d_out;

    const size_t FPREP_BYTES = (size_t)NFEAT * POUT * PIN * 2; // 442368
    if (ws_size < FPREP_BYTES + 256) {
        poly2d_fp32<<<dim3(8 * 64 * 16), dim3(256), 0, stream>>>(x, filt, bias, out);
        return;
    }
    _Float16* fprep = (_Float16*)d_ws;
    float* fconst = (float*)((char*)d_ws + FPREP_BYTES);

    prep_filters<<<dim3(64), dim3(256), 0, stream>>>(filt, bias, fprep, fconst);
    poly2d_mfma<<<dim3(256), dim3(512), 0, stream>>>(x, fprep, fconst, out);
}